// Round 9
// baseline (798.821 us; speedup 1.0000x reference)
//
#include <hip/hip_runtime.h>
#include <math.h>

#define NB   16
#define NPTS 2048
#define KNBR 20
#define NROWS (NB*NPTS)          // 32768
#define CONV_M ((double)(NB)*(double)(NPTS)*(double)(KNBR))
#define ROW_M  ((double)NROWS)
#define BN_EPS 1e-5
#define LSLOPE 0.2f

__device__ __forceinline__ float lrelu(float v) { return v >= 0.f ? v : LSLOPE * v; }

// candidate staging: (2x, 2y, 2z, -|p|^2)   query: (x, y, z, -|q|^2)
__device__ __forceinline__ float4 stage4(float px, float py, float pz)
{
    return make_float4(px + px, py + py, pz + pz,
                       -fmaf(px, px, fmaf(py, py, pz * pz)));
}

// d = 2<q,c> - |q|^2 - |c|^2  (same op order as all prior rounds)
__device__ __forceinline__ float dist_eval(float4 q, float4 c)
{
    float t = fmaf(c.x, q.x, fmaf(c.y, q.y, fmaf(c.z, q.z, q.w)));
    return t + c.w;
}

// ---- wave-wide bitonic primitives (64 lanes, 1 float/lane) ----------------
// keepmax lane-masks are compile-time constants -> v_cndmask with sgpr pair.
constexpr unsigned long long km_asc(int k, int j) {
    unsigned long long m = 0;
    for (int l = 0; l < 64; ++l) {
        bool up = ((l & k) == 0);                       // ascending-final sort
        bool km = up ? ((l & j) != 0) : ((l & j) == 0);
        if (km) m |= 1ull << l;
    }
    return m;
}
constexpr unsigned long long km_mrg(int j) {            // descending merge
    unsigned long long m = 0;
    for (int l = 0; l < 64; ++l)
        if ((l & j) == 0) m |= 1ull << l;
    return m;
}

template<unsigned long long KM>
__device__ __forceinline__ float cex_stage(float v, int j)
{
    float p = __shfl_xor(v, j);
    float mn = fminf(v, p), mx = fmaxf(v, p);
    float r;
    asm("v_cndmask_b32 %0, %1, %2, %3" : "=v"(r) : "v"(mn), "v"(mx), "s"(KM));
    return r;   // keepmax lanes take mx, others mn
}

__device__ __forceinline__ float sort64_asc(float v)
{
    v = cex_stage<km_asc(2,1)>(v,1);
    v = cex_stage<km_asc(4,2)>(v,2);   v = cex_stage<km_asc(4,1)>(v,1);
    v = cex_stage<km_asc(8,4)>(v,4);   v = cex_stage<km_asc(8,2)>(v,2);
    v = cex_stage<km_asc(8,1)>(v,1);
    v = cex_stage<km_asc(16,8)>(v,8);  v = cex_stage<km_asc(16,4)>(v,4);
    v = cex_stage<km_asc(16,2)>(v,2);  v = cex_stage<km_asc(16,1)>(v,1);
    v = cex_stage<km_asc(32,16)>(v,16);v = cex_stage<km_asc(32,8)>(v,8);
    v = cex_stage<km_asc(32,4)>(v,4);  v = cex_stage<km_asc(32,2)>(v,2);
    v = cex_stage<km_asc(32,1)>(v,1);
    v = cex_stage<km_asc(64,32)>(v,32);v = cex_stage<km_asc(64,16)>(v,16);
    v = cex_stage<km_asc(64,8)>(v,8);  v = cex_stage<km_asc(64,4)>(v,4);
    v = cex_stage<km_asc(64,2)>(v,2);  v = cex_stage<km_asc(64,1)>(v,1);
    return v;
}
__device__ __forceinline__ float merge64_desc(float v)
{
    v = cex_stage<km_mrg(32)>(v,32); v = cex_stage<km_mrg(16)>(v,16);
    v = cex_stage<km_mrg(8)>(v,8);   v = cex_stage<km_mrg(4)>(v,4);
    v = cex_stage<km_mrg(2)>(v,2);   v = cex_stage<km_mrg(1)>(v,1);
    return v;
}

__device__ __forceinline__ float lane_read(float v, int l)
{
    return __uint_as_float(__builtin_amdgcn_readlane(__float_as_uint(v), l));
}

// ---------------------------------------------------------------------------
// Fused KNN (wave-cooperative top-64 selection) + index recovery + edge-conv.
// Block = (b, 32 queries), 4 waves x 8 queries serially.
// Per query: scan 32 batches of 64 candidates (1/lane). Wave keeps top-64
//   sorted desc across lanes. Skip batch unless some d > current 64th
//   (wave-uniform branch, ~5/32 taken). Processed: bitonic sort-asc of the
//   new 64, elementwise max (bitonic halver = exact top-64 multiset), 6-stage
//   descending re-merge. thresh = lane 19 = exact 20th-largest.
// Recovery: ballot/prefix (d >= thresh), ascending order, tie-exact.
// ---------------------------------------------------------------------------
__global__ __launch_bounds__(256) void knn_feat_kernel(const float* __restrict__ x,
        const float* __restrict__ conv_w,
        float* __restrict__ maxh, float* __restrict__ minh, double* __restrict__ S)
{
    __shared__ float4 pts[NPTS];                       // 32 KB (2x,2y,2z,-xx)
    __shared__ unsigned short idxl[32][KNBR];
    __shared__ float  featw[4][KNBR][6];
    __shared__ double sred[4][27];
    __shared__ float  tbuf[32];
    const int b  = blockIdx.x >> 6;
    const int qg = blockIdx.x & 63;
    const int wv = threadIdx.x >> 6, lane = threadIdx.x & 63;
    const float* xb = x + (size_t)b * NPTS * 3;
    for (int i = threadIdx.x; i < NPTS; i += 256)
        pts[i] = stage4(xb[i*3+0], xb[i*3+1], xb[i*3+2]);
    __syncthreads();

    // ---- phase 0: exact 20th-largest distance per query ----
    for (int qi = 0; qi < 8; ++qi) {
        const int p = wv * 8 + qi;
        const int n = qg * 32 + p;
        const float4 qc = pts[n];
        const float4 q = make_float4(0.5f*qc.x, 0.5f*qc.y, 0.5f*qc.z, qc.w);
        float state = -__builtin_inff();
        for (int it = 0; it < 32; ++it) {
            float d = dist_eval(q, pts[it*64 + lane]);
            float smin = lane_read(state, 63);
            if (__any(d > smin)) {
                float nv = sort64_asc(d);
                state = fmaxf(state, nv);      // bitonic halver: top-64 multiset
                state = merge64_desc(state);
            }
        }
        if (lane == 0) tbuf[p] = lane_read(state, 19);
    }
    __syncthreads();

    // ---- recovery: wave per 8 queries, ballot/prefix, ascending m ----
    const unsigned long long below = (1ull << lane) - 1ull;
    for (int qi2 = 0; qi2 < 8; ++qi2) {
        const int p = wv * 8 + qi2;
        const int n = qg * 32 + p;
        const float4 qc = pts[n];
        const float4 q = make_float4(0.5f*qc.x, 0.5f*qc.y, 0.5f*qc.z, qc.w);
        const float th = tbuf[p];
        int cnt = 0;
        for (int it = 0; it < 32; ++it) {
            float d = dist_eval(q, pts[it*64 + lane]);
            const bool hit = (d >= th);
            unsigned long long mask = __ballot(hit);
            int pos = cnt + __popcll(mask & below);
            if (hit && pos < KNBR)
                idxl[p][pos] = (unsigned short)(it*64 + lane);
            cnt += __popcll(mask);
        }
    }
    __syncthreads();

    // ---- edge conv ----
    float cw[6];
#pragma unroll
    for (int c = 0; c < 6; ++c) cw[c] = conv_w[lane*6 + c];
    int pa_ = 0, pb_ = 0;
    if (lane >= 6 && lane < 27) {
        int t = lane - 6, a = 0;
        while (t >= 6 - a) { t -= 6 - a; ++a; }
        pa_ = a; pb_ = a + t;
    }
    double acc = 0.0;
    for (int i = 0; i < 8; ++i) {
        const int p = wv * 8 + i;
        const int nn = qg * 32 + p;
        const size_t bp = (size_t)b * NPTS + nn;
        const float4 Ci = pts[nn];
        const float xi0 = 0.5f*Ci.x, xi1 = 0.5f*Ci.y, xi2 = 0.5f*Ci.z;
        float f0=0,f1=0,f2=0,f3=0,f4=0,f5=0;
        if (lane < KNBR) {
            const float4 Cj = pts[idxl[p][lane]];
            f0 = 0.5f*(Cj.x - Ci.x);   // == fl(xj - xi) exactly
            f1 = 0.5f*(Cj.y - Ci.y);
            f2 = 0.5f*(Cj.z - Ci.z);
            f3 = xi0; f4 = xi1; f5 = xi2;
        }
        __syncthreads();
        if (lane < KNBR) {
            featw[wv][lane][0]=f0; featw[wv][lane][1]=f1; featw[wv][lane][2]=f2;
            featw[wv][lane][3]=f3; featw[wv][lane][4]=f4; featw[wv][lane][5]=f5;
        }
        __syncthreads();
        float vmax = -__builtin_inff(), vmin = __builtin_inff();
#pragma unroll
        for (int k = 0; k < KNBR; ++k) {
            float h = featw[wv][k][0] * cw[0];
            h = fmaf(featw[wv][k][1], cw[1], h);
            h = fmaf(featw[wv][k][2], cw[2], h);
            h = fmaf(featw[wv][k][3], cw[3], h);
            h = fmaf(featw[wv][k][4], cw[4], h);
            h = fmaf(featw[wv][k][5], cw[5], h);
            vmax = fmaxf(vmax, h); vmin = fminf(vmin, h);
        }
        maxh[bp*64 + lane] = vmax;
        minh[bp*64 + lane] = vmin;
        if (lane < 6) {
            double s = 0;
#pragma unroll
            for (int k = 0; k < KNBR; ++k) s += (double)featw[wv][k][lane];
            acc += s;
        } else if (lane < 27) {
            double s = 0;
#pragma unroll
            for (int k = 0; k < KNBR; ++k)
                s += (double)featw[wv][k][pa_] * (double)featw[wv][k][pb_];
            acc += s;
        }
    }
    if (lane < 27) sred[wv][lane] = acc;
    __syncthreads();
    if (threadIdx.x < 27) {
        double tot = sred[0][threadIdx.x] + sred[1][threadIdx.x]
                   + sred[2][threadIdx.x] + sred[3][threadIdx.x];
        atomicAdd(&S[threadIdx.x], tot);
    }
}

// ---------------------------------------------------------------------------
// MLP GEMM with in-kernel BN scale/shift derivation (identical double math
// per block -> identical floats).
// ---------------------------------------------------------------------------
template<int K, int N, bool SEL, bool POOLOUT, bool STATS0>
__global__ __launch_bounds__(256) void mlp_gemm(const float* __restrict__ A,
        const float* __restrict__ A2,
        const double* __restrict__ st_a, const double* __restrict__ st_b,
        const float* __restrict__ st_g, const float* __restrict__ st_bt,
        const float* __restrict__ cwm,
        const float* __restrict__ W, const float* __restrict__ bias,
        float* __restrict__ Y, double* __restrict__ sum, double* __restrict__ sq,
        float* __restrict__ pmax_g, float* __restrict__ pmin_g)
{
    constexpr int CPT = N / 16;                 // cols per thread (4 or 8)
    __shared__ float As[64 * 64];               // [k][row^swz], 16 KB
    __shared__ float Ws[64 * N];                // [k][n]
    __shared__ __align__(16) float s_scale[K], s_shift[K];
    const int tid = threadIdx.x;
    if (tid < K) {
        const int o = tid;
        if (STATS0) {
            double w[6];
#pragma unroll
            for (int c = 0; c < 6; ++c) w[c] = (double)cwm[o*6 + c];
            double mean = 0.0;
#pragma unroll
            for (int c = 0; c < 6; ++c) mean += w[c] * st_a[c];
            mean /= CONV_M;
            double ey2 = 0.0;
            int t = 6;
#pragma unroll
            for (int a = 0; a < 6; ++a)
#pragma unroll
                for (int b2 = a; b2 < 6; ++b2) {
                    double coef = (a == b2) ? 1.0 : 2.0;
                    ey2 += coef * w[a] * w[b2] * st_a[t];
                    ++t;
                }
            ey2 /= CONV_M;
            double var = ey2 - mean * mean;
            double sc = (double)st_g[o] / sqrt(var + BN_EPS);
            s_scale[o] = (float)sc;
            s_shift[o] = (float)((double)st_bt[o] - mean * sc);
        } else {
            double m = st_a[o] / ROW_M;
            double v = st_b[o] / ROW_M - m * m;
            double sc = (double)st_g[o] / sqrt(v + BN_EPS);
            s_scale[o] = (float)sc;
            s_shift[o] = (float)((double)st_bt[o] - m * sc);
        }
    }
    const int row0 = blockIdx.x * 64;
    const int ct = tid & 15, rt = tid >> 4;
    float acc[4][CPT];
#pragma unroll
    for (int rr = 0; rr < 4; ++rr)
#pragma unroll
        for (int cc = 0; cc < CPT; ++cc) acc[rr][cc] = bias[ct*CPT + cc];
    __syncthreads();

    for (int kk = 0; kk < K/64; ++kk) {
        if (kk) __syncthreads();
#pragma unroll
        for (int i = 0; i < 4; ++i) {
            const int f   = i * 256 + tid;
            const int k4  = f & 15;
            const int row = f >> 4;
            const int kg  = kk*64 + k4*4;
            float4 m = *(const float4*)(A + (size_t)(row0+row)*K + kg);
            const float4 s4 = *(const float4*)(&s_scale[kg]);
            const float4 h4 = *(const float4*)(&s_shift[kg]);
            if (SEL) {
                float4 m2 = *(const float4*)(A2 + (size_t)(row0+row)*K + kg);
                m.x = s4.x >= 0.f ? m.x : m2.x;
                m.y = s4.y >= 0.f ? m.y : m2.y;
                m.z = s4.z >= 0.f ? m.z : m2.z;
                m.w = s4.w >= 0.f ? m.w : m2.w;
            }
            const int rsw = row ^ ((k4 & 7) << 2);
            As[(k4*4+0)*64 + rsw] = lrelu(fmaf(s4.x, m.x, h4.x));
            As[(k4*4+1)*64 + rsw] = lrelu(fmaf(s4.y, m.y, h4.y));
            As[(k4*4+2)*64 + rsw] = lrelu(fmaf(s4.z, m.z, h4.z));
            As[(k4*4+3)*64 + rsw] = lrelu(fmaf(s4.w, m.w, h4.w));
        }
#pragma unroll
        for (int i = 0; i < N/16; ++i) {
            const int f    = i * 256 + tid;
            const int col4 = f & (N/4 - 1);
            const int krow = f / (N/4);
            *(float4*)(&Ws[krow*N + col4*4]) =
                *(const float4*)(W + (size_t)(kk*64 + krow)*N + col4*4);
        }
        __syncthreads();
#pragma unroll 4
        for (int k = 0; k < 64; ++k) {
            const int sw = ((k >> 2) & 7) << 2;
            const float4 a0 = *(const float4*)(&As[k*64 + ((rt*4) ^ sw)]);
            float a_[4] = {a0.x, a0.y, a0.z, a0.w};
            float w_[CPT];
#pragma unroll
            for (int v = 0; v < CPT/4; ++v) {
                const float4 wv4 = *(const float4*)(&Ws[k*N + ct*CPT + v*4]);
                w_[v*4+0] = wv4.x; w_[v*4+1] = wv4.y; w_[v*4+2] = wv4.z; w_[v*4+3] = wv4.w;
            }
#pragma unroll
            for (int rr = 0; rr < 4; ++rr)
#pragma unroll
                for (int cc = 0; cc < CPT; ++cc)
                    acc[rr][cc] = fmaf(a_[rr], w_[cc], acc[rr][cc]);
        }
    }
    if (!POOLOUT) {
#pragma unroll
        for (int rr = 0; rr < 4; ++rr) {
            float* yo = Y + (size_t)(row0 + rt*4 + rr)*N + ct*CPT;
#pragma unroll
            for (int v = 0; v < CPT/4; ++v)
                *(float4*)(yo + v*4) = make_float4(acc[rr][v*4+0], acc[rr][v*4+1],
                                                   acc[rr][v*4+2], acc[rr][v*4+3]);
        }
    }
    __syncthreads();                  // LDS dead; reuse As/Ws
    float* cr  = As;                  // [2N] column sum/sq partials
    float* pmx = As + 512;            // [16][N] per-rt max
    float* pmn = Ws;                  // [16][N] per-rt min
    if (tid < 2*N) cr[tid] = 0.f;
    if (POOLOUT) {
#pragma unroll
        for (int cc = 0; cc < CPT; ++cc) {
            float vmax = fmaxf(fmaxf(acc[0][cc], acc[1][cc]), fmaxf(acc[2][cc], acc[3][cc]));
            float vmin = fminf(fminf(acc[0][cc], acc[1][cc]), fminf(acc[2][cc], acc[3][cc]));
            pmx[rt*N + ct*CPT + cc] = vmax;
            pmn[rt*N + ct*CPT + cc] = vmin;
        }
    }
    __syncthreads();
#pragma unroll
    for (int cc = 0; cc < CPT; ++cc) {
        float s = acc[0][cc] + acc[1][cc] + acc[2][cc] + acc[3][cc];
        float q = fmaf(acc[0][cc], acc[0][cc], 0.f);
        q = fmaf(acc[1][cc], acc[1][cc], q);
        q = fmaf(acc[2][cc], acc[2][cc], q);
        q = fmaf(acc[3][cc], acc[3][cc], q);
        atomicAdd(&cr[ct*CPT + cc], s);
        atomicAdd(&cr[N + ct*CPT + cc], q);
    }
    float rm = 0.f, rn = 0.f;
    if (POOLOUT && tid < N) {
        rm = pmx[tid]; rn = pmn[tid];
#pragma unroll
        for (int r = 1; r < 16; ++r) {
            rm = fmaxf(rm, pmx[r*N + tid]);
            rn = fminf(rn, pmn[r*N + tid]);
        }
    }
    __syncthreads();
    if (tid < N) {
        atomicAdd(&sum[tid], (double)cr[tid]);
        atomicAdd(&sq[tid],  (double)cr[N + tid]);
        if (POOLOUT) {
            pmax_g[(size_t)blockIdx.x * N + tid] = rm;
            pmin_g[(size_t)blockIdx.x * N + tid] = rn;
        }
    }
}

// ---------------------------------------------------------------------------
// Fused BN3-derive + pool-finish + head. Block = batch b.
// ---------------------------------------------------------------------------
__global__ __launch_bounds__(256) void headpool_kernel(const float* __restrict__ pmax_g,
        const float* __restrict__ pmin_g,
        const double* __restrict__ sum3, const double* __restrict__ sq3,
        const float* __restrict__ g3, const float* __restrict__ bt3,
        const float* __restrict__ w4, const float* __restrict__ b4,
        const float* __restrict__ w5, const float* __restrict__ b5,
        float* __restrict__ out)
{
    __shared__ float xr[128];
    __shared__ float hh[512];
    const int b = blockIdx.x, t = threadIdx.x;
    if (t < 128) {
        double m_ = sum3[t] / ROW_M;
        double v_ = sq3[t] / ROW_M - m_ * m_;
        double scd = (double)g3[t] / sqrt(v_ + BN_EPS);
        const float sc = (float)scd;
        const float sh = (float)((double)bt3[t] - m_ * scd);
        const float* pm = pmax_g + (size_t)b * 32 * 128 + t;
        const float* pn = pmin_g + (size_t)b * 32 * 128 + t;
        float m = pm[0], n_ = pn[0];
#pragma unroll
        for (int r = 1; r < 32; ++r) {
            m  = fmaxf(m,  pm[r*128]);
            n_ = fminf(n_, pn[r*128]);
        }
        xr[t] = lrelu(sc >= 0.f ? fmaf(sc, m, sh) : fmaf(sc, n_, sh));
    }
    __syncthreads();
    float h0 = b4[t], h1 = b4[t + 256];
    for (int c = 0; c < 128; ++c) {
        float xc = xr[c];
        h0 = fmaf(xc, w4[c*512 + t],       h0);
        h1 = fmaf(xc, w4[c*512 + t + 256], h1);
    }
    hh[t]       = lrelu(h0);
    hh[t + 256] = lrelu(h1);
    __syncthreads();
    float acc = b5[t];
    for (int c = 0; c < 512; ++c)
        acc = fmaf(hh[c], w5[c*256 + t], acc);
    out[b*256 + t] = acc;
}

extern "C" void kernel_launch(void* const* d_in, const int* in_sizes, int n_in,
                              void* d_out, int out_size, void* d_ws, size_t ws_size,
                              hipStream_t stream)
{
    const float* x      = (const float*)d_in[0];
    const float* conv_w = (const float*)d_in[1];
    const float* conv_g = (const float*)d_in[2];
    const float* conv_b = (const float*)d_in[3];
    const float* w1  = (const float*)d_in[4];
    const float* b1  = (const float*)d_in[5];
    const float* g1  = (const float*)d_in[6];
    const float* bt1 = (const float*)d_in[7];
    const float* w2  = (const float*)d_in[8];
    const float* b2  = (const float*)d_in[9];
    const float* g2  = (const float*)d_in[10];
    const float* bt2 = (const float*)d_in[11];
    const float* w3  = (const float*)d_in[12];
    const float* b3  = (const float*)d_in[13];
    const float* g3  = (const float*)d_in[14];
    const float* bt3 = (const float*)d_in[15];
    const float* w4  = (const float*)d_in[16];
    const float* b4  = (const float*)d_in[17];
    const float* w5  = (const float*)d_in[18];
    const float* b5  = (const float*)d_in[19];

    char* p = (char*)d_ws;
    auto take = [&](size_t bytes) -> char* {
        char* r = p; p += (bytes + 255) & ~(size_t)255; return r;
    };
    double* S    = (double*)take(27 * 8);
    double* sum1 = (double*)take(64 * 8);
    double* sq1  = (double*)take(64 * 8);
    double* sum2 = (double*)take(128 * 8);
    double* sq2  = (double*)take(128 * 8);
    double* sum3 = (double*)take(128 * 8);
    double* sq3  = (double*)take(128 * 8);
    size_t zero_bytes = (size_t)(p - (char*)d_ws);
    float* pmaxg  = (float*)take((size_t)512 * 128 * 4);     // 256 KB
    float* pming  = (float*)take((size_t)512 * 128 * 4);     // 256 KB
    float* mm     = (float*)take((size_t)NROWS * 128 * 4);   // 16 MB
    float* maxh   = mm;
    float* minh   = mm + (size_t)NROWS * 64;
    float* y1     = (float*)take((size_t)NROWS * 64 * 4);    // 8 MB
    float* y2     = (float*)take((size_t)NROWS * 128 * 4);   // 16 MB

    hipMemsetAsync(d_ws, 0, zero_bytes, stream);
    knn_feat_kernel<<<dim3(NB * 64), dim3(256), 0, stream>>>(x, conv_w, maxh, minh, S);

    mlp_gemm<64,64,true,false,true>    <<<dim3(512), dim3(256), 0, stream>>>(
        maxh, minh, S, nullptr, conv_g, conv_b, conv_w, w1, b1, y1, sum1, sq1, nullptr, nullptr);
    mlp_gemm<64,128,false,false,false> <<<dim3(512), dim3(256), 0, stream>>>(
        y1, y1, sum1, sq1, g1, bt1, nullptr, w2, b2, y2, sum2, sq2, nullptr, nullptr);
    mlp_gemm<128,128,false,true,false> <<<dim3(512), dim3(256), 0, stream>>>(
        y2, y2, sum2, sq2, g2, bt2, nullptr, w3, b3, nullptr, sum3, sq3, pmaxg, pming);

    headpool_kernel<<<dim3(NB), dim3(256), 0, stream>>>(
        pmaxg, pming, sum3, sq3, g3, bt3, w4, b4, w5, b5, (float*)d_out);
}

// Round 10
// 417.681 us; speedup vs baseline: 1.9125x; 1.9125x over previous
//
#include <hip/hip_runtime.h>
#include <math.h>

#define NB   16
#define NPTS 2048
#define KNBR 20
#define SCAP 120                 // survivor cap per query (E~80, +2.7 sigma)
#define NROWS (NB*NPTS)          // 32768
#define CONV_M ((double)(NB)*(double)(NPTS)*(double)(KNBR))
#define ROW_M  ((double)NROWS)
#define BN_EPS 1e-5
#define LSLOPE 0.2f

__device__ __forceinline__ float lrelu(float v) { return v >= 0.f ? v : LSLOPE * v; }

// candidate staging: (2x, 2y, 2z, -|p|^2)   query: (x, y, z, -|q|^2)
__device__ __forceinline__ float4 stage4(float px, float py, float pz)
{
    return make_float4(px + px, py + py, pz + pz,
                       -fmaf(px, px, fmaf(py, py, pz * pz)));
}

// d = 2<q,c> - |q|^2 - |c|^2  (same op order as all prior rounds)
__device__ __forceinline__ float dist_eval(float4 q, float4 c)
{
    float t = fmaf(c.x, q.x, fmaf(c.y, q.y, fmaf(c.z, q.z, q.w)));
    return t + c.w;
}

// pair-insert of sorted (t0 >= t1) into sorted-desc bestv[20]
__device__ __forceinline__ void pair_insert_sorted(float (&bestv)[KNBR], float t0, float t1)
{
#pragma unroll
    for (int j = 0; j < KNBR; ++j) {
        float bj = bestv[j];
        float nb  = fmaxf(bj, t0);
        float nt0 = __builtin_amdgcn_fmed3f(bj, t0, t1);
        float nt1 = fminf(bj, t1);
        bestv[j] = nb;
        t0 = nt0; t1 = nt1;
    }
}

// order-preserving f32 <-> u32 map
__device__ __forceinline__ unsigned omap(float f)
{
    unsigned b = __float_as_uint(f);
    return b ^ (unsigned)(((int)b >> 31) | (int)0x80000000);
}
__device__ __forceinline__ float ounmap(unsigned u)
{
    unsigned b = (u & 0x80000000u) ? (u ^ 0x80000000u) : ~u;
    return __uint_as_float(b);
}

// ---------------------------------------------------------------------------
// Fused KNN (sample-bound -> filter -> bisect-select) + index recovery +
// edge-conv. Block = (b, 32 queries), 256 threads.
// A: thread=(query,64-chunk of first 512): lane-local pair-cascade top-20 +
//    shfl tree-merge -> L = exact 20th of 512-sample (lower bound on d20).
// B: wave-per-query full scan; ballot-compact survivor VALUES (d >= L).
// C: 32-step uint bisection counting over survivors (<=2/lane) -> exact d20;
//    overflow fallback re-evaluates (rare, still exact).
// Recovery: ballot/prefix rescan (d >= thresh), ascending, tie-exact.
// ---------------------------------------------------------------------------
__global__ __launch_bounds__(256) void knn_feat_kernel(const float* __restrict__ x,
        const float* __restrict__ conv_w,
        float* __restrict__ maxh, float* __restrict__ minh, double* __restrict__ S)
{
    __shared__ float4 pts[NPTS];                       // 32 KB
    __shared__ float  sval[32][SCAP];                  // 15 KB survivor values
    __shared__ float  tbuf[32];                        // L per query
    __shared__ int    scnt[32];
    __shared__ unsigned short idxl[32][KNBR];
    __shared__ float  featw[4][KNBR][6];
    __shared__ double sred[4][27];
    const int b  = blockIdx.x >> 6;
    const int qg = blockIdx.x & 63;
    const int wv = threadIdx.x >> 6, lane = threadIdx.x & 63;
    const float* xb = x + (size_t)b * NPTS * 3;
    for (int i = threadIdx.x; i < NPTS; i += 256)
        pts[i] = stage4(xb[i*3+0], xb[i*3+1], xb[i*3+2]);
    __syncthreads();

    // ---- phase A: sample lower bound L (thread = query x 64-chunk) ----
    {
        const int qi = threadIdx.x >> 3;       // 0..31
        const int c  = threadIdx.x & 7;        // chunk 0..7 of first 512
        const int n  = qg * 32 + qi;
        const float4 qc = pts[n];
        const float4 q = make_float4(0.5f*qc.x, 0.5f*qc.y, 0.5f*qc.z, qc.w);
        float bestv[KNBR];
#pragma unroll
        for (int j = 0; j < KNBR; ++j) bestv[j] = -__builtin_inff();
        for (int m = 0; m < 64; m += 2) {
            const int j0 = c*64 + ((m + c) & 63);      // bank-spread rotation
            const int j1 = c*64 + ((m + 1 + c) & 63);
            float d0 = dist_eval(q, pts[j0]);
            float d1 = dist_eval(q, pts[j1]);
            pair_insert_sorted(bestv, fmaxf(d0, d1), fminf(d0, d1));
        }
        // tree-merge over the 8 chunk-threads (lanes differ in bits 0..2)
#pragma unroll
        for (int lev = 1; lev <= 4; lev <<= 1) {
            float orig[KNBR];
#pragma unroll
            for (int j = 0; j < KNBR; ++j) orig[j] = bestv[j];
            for (int i = 0; i < KNBR; i += 2) {
                float nb0 = __shfl_xor(orig[i],   lev);
                float nb1 = __shfl_xor(orig[i+1], lev);
                if (!__any(nb0 > bestv[KNBR-1])) break;
                pair_insert_sorted(bestv, nb0, nb1);
            }
        }
        if (c == 0) tbuf[qi] = bestv[KNBR-1];   // L = exact 20th of 512-sample
    }
    // no barrier needed: tbuf/sval/scnt/idxl flow is same-wave throughout

    // ---- phases B/C + recovery, wave per 8 queries ----
    const unsigned long long below = (1ull << lane) - 1ull;
    for (int qi2 = 0; qi2 < 8; ++qi2) {
        const int p = wv * 8 + qi2;
        const int n = qg * 32 + p;
        const float4 qc = pts[n];
        const float4 q = make_float4(0.5f*qc.x, 0.5f*qc.y, 0.5f*qc.z, qc.w);
        const float L = tbuf[p];
        // B: filter + compact survivor values
        int cnt = 0;
        for (int it = 0; it < 32; ++it) {
            float d = dist_eval(q, pts[it*64 + lane]);
            const bool hit = (d >= L);
            unsigned long long mask = __ballot(hit);
            int pos = cnt + __popcll(mask & below);
            if (hit && pos < SCAP) sval[p][pos] = d;
            cnt += __popcll(mask);
        }
        // C: exact 20th-largest via 32-step bisection
        float thresh;
        if (cnt <= SCAP) {
            unsigned u0 = (lane      < cnt) ? omap(sval[p][lane])      : 0u;
            unsigned u1 = (lane + 64 < cnt) ? omap(sval[p][lane + 64]) : 0u;
            unsigned lo = 0u, hi = 0xFFFFFFFFu;
#pragma unroll
            for (int s = 0; s < 32; ++s) {
                unsigned mid = lo + ((hi - lo) >> 1);
                int c2 = __popcll(__ballot(u0 >= mid)) + __popcll(__ballot(u1 >= mid));
                bool ge = (c2 >= KNBR);
                lo = ge ? mid : lo;
                hi = ge ? hi : mid;
            }
            thresh = ounmap(lo);
        } else {
            // rare overflow: bisect with re-evaluated distances (still exact)
            unsigned lo = 0u, hi = 0xFFFFFFFFu;
            for (int s = 0; s < 32; ++s) {
                unsigned mid = lo + ((hi - lo) >> 1);
                int c2 = 0;
                for (int it = 0; it < 32; ++it) {
                    float d = dist_eval(q, pts[it*64 + lane]);
                    c2 += __popcll(__ballot(omap(d) >= mid));
                }
                bool ge = (c2 >= KNBR);
                lo = ge ? mid : lo;
                hi = ge ? hi : mid;
            }
            thresh = ounmap(lo);
        }
        // recovery: ballot/prefix rescan, ascending m, tie-exact
        int cnt2 = 0;
        for (int it = 0; it < 32; ++it) {
            float d = dist_eval(q, pts[it*64 + lane]);
            const bool hit = (d >= thresh);
            unsigned long long mask = __ballot(hit);
            int pos = cnt2 + __popcll(mask & below);
            if (hit && pos < KNBR)
                idxl[p][pos] = (unsigned short)(it*64 + lane);
            cnt2 += __popcll(mask);
        }
    }

    // ---- edge conv (unchanged; all reads same-wave or stable pts) ----
    float cw[6];
#pragma unroll
    for (int c = 0; c < 6; ++c) cw[c] = conv_w[lane*6 + c];
    int pa_ = 0, pb_ = 0;
    if (lane >= 6 && lane < 27) {
        int t = lane - 6, a = 0;
        while (t >= 6 - a) { t -= 6 - a; ++a; }
        pa_ = a; pb_ = a + t;
    }
    double acc = 0.0;
    for (int i = 0; i < 8; ++i) {
        const int p = wv * 8 + i;
        const int nn = qg * 32 + p;
        const size_t bp = (size_t)b * NPTS + nn;
        const float4 Ci = pts[nn];
        const float xi0 = 0.5f*Ci.x, xi1 = 0.5f*Ci.y, xi2 = 0.5f*Ci.z;
        float f0=0,f1=0,f2=0,f3=0,f4=0,f5=0;
        if (lane < KNBR) {
            const float4 Cj = pts[idxl[p][lane]];
            f0 = 0.5f*(Cj.x - Ci.x);   // == fl(xj - xi) exactly
            f1 = 0.5f*(Cj.y - Ci.y);
            f2 = 0.5f*(Cj.z - Ci.z);
            f3 = xi0; f4 = xi1; f5 = xi2;
        }
        __syncthreads();
        if (lane < KNBR) {
            featw[wv][lane][0]=f0; featw[wv][lane][1]=f1; featw[wv][lane][2]=f2;
            featw[wv][lane][3]=f3; featw[wv][lane][4]=f4; featw[wv][lane][5]=f5;
        }
        __syncthreads();
        float vmax = -__builtin_inff(), vmin = __builtin_inff();
#pragma unroll
        for (int k = 0; k < KNBR; ++k) {
            float h = featw[wv][k][0] * cw[0];
            h = fmaf(featw[wv][k][1], cw[1], h);
            h = fmaf(featw[wv][k][2], cw[2], h);
            h = fmaf(featw[wv][k][3], cw[3], h);
            h = fmaf(featw[wv][k][4], cw[4], h);
            h = fmaf(featw[wv][k][5], cw[5], h);
            vmax = fmaxf(vmax, h); vmin = fminf(vmin, h);
        }
        maxh[bp*64 + lane] = vmax;
        minh[bp*64 + lane] = vmin;
        if (lane < 6) {
            double s = 0;
#pragma unroll
            for (int k = 0; k < KNBR; ++k) s += (double)featw[wv][k][lane];
            acc += s;
        } else if (lane < 27) {
            double s = 0;
#pragma unroll
            for (int k = 0; k < KNBR; ++k)
                s += (double)featw[wv][k][pa_] * (double)featw[wv][k][pb_];
            acc += s;
        }
    }
    if (lane < 27) sred[wv][lane] = acc;
    __syncthreads();
    if (threadIdx.x < 27) {
        double tot = sred[0][threadIdx.x] + sred[1][threadIdx.x]
                   + sred[2][threadIdx.x] + sred[3][threadIdx.x];
        atomicAdd(&S[threadIdx.x], tot);
    }
}

// ---------------------------------------------------------------------------
// MLP GEMM with in-kernel BN scale/shift derivation (identical double math
// per block -> identical floats).
// ---------------------------------------------------------------------------
template<int K, int N, bool SEL, bool POOLOUT, bool STATS0>
__global__ __launch_bounds__(256) void mlp_gemm(const float* __restrict__ A,
        const float* __restrict__ A2,
        const double* __restrict__ st_a, const double* __restrict__ st_b,
        const float* __restrict__ st_g, const float* __restrict__ st_bt,
        const float* __restrict__ cwm,
        const float* __restrict__ W, const float* __restrict__ bias,
        float* __restrict__ Y, double* __restrict__ sum, double* __restrict__ sq,
        float* __restrict__ pmax_g, float* __restrict__ pmin_g)
{
    constexpr int CPT = N / 16;                 // cols per thread (4 or 8)
    __shared__ float As[64 * 64];               // [k][row^swz], 16 KB
    __shared__ float Ws[64 * N];                // [k][n]
    __shared__ __align__(16) float s_scale[K], s_shift[K];
    const int tid = threadIdx.x;
    if (tid < K) {
        const int o = tid;
        if (STATS0) {
            double w[6];
#pragma unroll
            for (int c = 0; c < 6; ++c) w[c] = (double)cwm[o*6 + c];
            double mean = 0.0;
#pragma unroll
            for (int c = 0; c < 6; ++c) mean += w[c] * st_a[c];
            mean /= CONV_M;
            double ey2 = 0.0;
            int t = 6;
#pragma unroll
            for (int a = 0; a < 6; ++a)
#pragma unroll
                for (int b2 = a; b2 < 6; ++b2) {
                    double coef = (a == b2) ? 1.0 : 2.0;
                    ey2 += coef * w[a] * w[b2] * st_a[t];
                    ++t;
                }
            ey2 /= CONV_M;
            double var = ey2 - mean * mean;
            double sc = (double)st_g[o] / sqrt(var + BN_EPS);
            s_scale[o] = (float)sc;
            s_shift[o] = (float)((double)st_bt[o] - mean * sc);
        } else {
            double m = st_a[o] / ROW_M;
            double v = st_b[o] / ROW_M - m * m;
            double sc = (double)st_g[o] / sqrt(v + BN_EPS);
            s_scale[o] = (float)sc;
            s_shift[o] = (float)((double)st_bt[o] - m * sc);
        }
    }
    const int row0 = blockIdx.x * 64;
    const int ct = tid & 15, rt = tid >> 4;
    float acc[4][CPT];
#pragma unroll
    for (int rr = 0; rr < 4; ++rr)
#pragma unroll
        for (int cc = 0; cc < CPT; ++cc) acc[rr][cc] = bias[ct*CPT + cc];
    __syncthreads();

    for (int kk = 0; kk < K/64; ++kk) {
        if (kk) __syncthreads();
#pragma unroll
        for (int i = 0; i < 4; ++i) {
            const int f   = i * 256 + tid;
            const int k4  = f & 15;
            const int row = f >> 4;
            const int kg  = kk*64 + k4*4;
            float4 m = *(const float4*)(A + (size_t)(row0+row)*K + kg);
            const float4 s4 = *(const float4*)(&s_scale[kg]);
            const float4 h4 = *(const float4*)(&s_shift[kg]);
            if (SEL) {
                float4 m2 = *(const float4*)(A2 + (size_t)(row0+row)*K + kg);
                m.x = s4.x >= 0.f ? m.x : m2.x;
                m.y = s4.y >= 0.f ? m.y : m2.y;
                m.z = s4.z >= 0.f ? m.z : m2.z;
                m.w = s4.w >= 0.f ? m.w : m2.w;
            }
            const int rsw = row ^ ((k4 & 7) << 2);
            As[(k4*4+0)*64 + rsw] = lrelu(fmaf(s4.x, m.x, h4.x));
            As[(k4*4+1)*64 + rsw] = lrelu(fmaf(s4.y, m.y, h4.y));
            As[(k4*4+2)*64 + rsw] = lrelu(fmaf(s4.z, m.z, h4.z));
            As[(k4*4+3)*64 + rsw] = lrelu(fmaf(s4.w, m.w, h4.w));
        }
#pragma unroll
        for (int i = 0; i < N/16; ++i) {
            const int f    = i * 256 + tid;
            const int col4 = f & (N/4 - 1);
            const int krow = f / (N/4);
            *(float4*)(&Ws[krow*N + col4*4]) =
                *(const float4*)(W + (size_t)(kk*64 + krow)*N + col4*4);
        }
        __syncthreads();
#pragma unroll 4
        for (int k = 0; k < 64; ++k) {
            const int sw = ((k >> 2) & 7) << 2;
            const float4 a0 = *(const float4*)(&As[k*64 + ((rt*4) ^ sw)]);
            float a_[4] = {a0.x, a0.y, a0.z, a0.w};
            float w_[CPT];
#pragma unroll
            for (int v = 0; v < CPT/4; ++v) {
                const float4 wv4 = *(const float4*)(&Ws[k*N + ct*CPT + v*4]);
                w_[v*4+0] = wv4.x; w_[v*4+1] = wv4.y; w_[v*4+2] = wv4.z; w_[v*4+3] = wv4.w;
            }
#pragma unroll
            for (int rr = 0; rr < 4; ++rr)
#pragma unroll
                for (int cc = 0; cc < CPT; ++cc)
                    acc[rr][cc] = fmaf(a_[rr], w_[cc], acc[rr][cc]);
        }
    }
    if (!POOLOUT) {
#pragma unroll
        for (int rr = 0; rr < 4; ++rr) {
            float* yo = Y + (size_t)(row0 + rt*4 + rr)*N + ct*CPT;
#pragma unroll
            for (int v = 0; v < CPT/4; ++v)
                *(float4*)(yo + v*4) = make_float4(acc[rr][v*4+0], acc[rr][v*4+1],
                                                   acc[rr][v*4+2], acc[rr][v*4+3]);
        }
    }
    __syncthreads();                  // LDS dead; reuse As/Ws
    float* cr  = As;                  // [2N] column sum/sq partials
    float* pmx = As + 512;            // [16][N] per-rt max
    float* pmn = Ws;                  // [16][N] per-rt min
    if (tid < 2*N) cr[tid] = 0.f;
    if (POOLOUT) {
#pragma unroll
        for (int cc = 0; cc < CPT; ++cc) {
            float vmax = fmaxf(fmaxf(acc[0][cc], acc[1][cc]), fmaxf(acc[2][cc], acc[3][cc]));
            float vmin = fminf(fminf(acc[0][cc], acc[1][cc]), fminf(acc[2][cc], acc[3][cc]));
            pmx[rt*N + ct*CPT + cc] = vmax;
            pmn[rt*N + ct*CPT + cc] = vmin;
        }
    }
    __syncthreads();
#pragma unroll
    for (int cc = 0; cc < CPT; ++cc) {
        float s = acc[0][cc] + acc[1][cc] + acc[2][cc] + acc[3][cc];
        float q = fmaf(acc[0][cc], acc[0][cc], 0.f);
        q = fmaf(acc[1][cc], acc[1][cc], q);
        q = fmaf(acc[2][cc], acc[2][cc], q);
        q = fmaf(acc[3][cc], acc[3][cc], q);
        atomicAdd(&cr[ct*CPT + cc], s);
        atomicAdd(&cr[N + ct*CPT + cc], q);
    }
    float rm = 0.f, rn = 0.f;
    if (POOLOUT && tid < N) {
        rm = pmx[tid]; rn = pmn[tid];
#pragma unroll
        for (int r = 1; r < 16; ++r) {
            rm = fmaxf(rm, pmx[r*N + tid]);
            rn = fminf(rn, pmn[r*N + tid]);
        }
    }
    __syncthreads();
    if (tid < N) {
        atomicAdd(&sum[tid], (double)cr[tid]);
        atomicAdd(&sq[tid],  (double)cr[N + tid]);
        if (POOLOUT) {
            pmax_g[(size_t)blockIdx.x * N + tid] = rm;
            pmin_g[(size_t)blockIdx.x * N + tid] = rn;
        }
    }
}

// ---------------------------------------------------------------------------
// Fused BN3-derive + pool-finish + head. Block = batch b.
// ---------------------------------------------------------------------------
__global__ __launch_bounds__(256) void headpool_kernel(const float* __restrict__ pmax_g,
        const float* __restrict__ pmin_g,
        const double* __restrict__ sum3, const double* __restrict__ sq3,
        const float* __restrict__ g3, const float* __restrict__ bt3,
        const float* __restrict__ w4, const float* __restrict__ b4,
        const float* __restrict__ w5, const float* __restrict__ b5,
        float* __restrict__ out)
{
    __shared__ float xr[128];
    __shared__ float hh[512];
    const int b = blockIdx.x, t = threadIdx.x;
    if (t < 128) {
        double m_ = sum3[t] / ROW_M;
        double v_ = sq3[t] / ROW_M - m_ * m_;
        double scd = (double)g3[t] / sqrt(v_ + BN_EPS);
        const float sc = (float)scd;
        const float sh = (float)((double)bt3[t] - m_ * scd);
        const float* pm = pmax_g + (size_t)b * 32 * 128 + t;
        const float* pn = pmin_g + (size_t)b * 32 * 128 + t;
        float m = pm[0], n_ = pn[0];
#pragma unroll
        for (int r = 1; r < 32; ++r) {
            m  = fmaxf(m,  pm[r*128]);
            n_ = fminf(n_, pn[r*128]);
        }
        xr[t] = lrelu(sc >= 0.f ? fmaf(sc, m, sh) : fmaf(sc, n_, sh));
    }
    __syncthreads();
    float h0 = b4[t], h1 = b4[t + 256];
    for (int c = 0; c < 128; ++c) {
        float xc = xr[c];
        h0 = fmaf(xc, w4[c*512 + t],       h0);
        h1 = fmaf(xc, w4[c*512 + t + 256], h1);
    }
    hh[t]       = lrelu(h0);
    hh[t + 256] = lrelu(h1);
    __syncthreads();
    float acc = b5[t];
    for (int c = 0; c < 512; ++c)
        acc = fmaf(hh[c], w5[c*256 + t], acc);
    out[b*256 + t] = acc;
}

extern "C" void kernel_launch(void* const* d_in, const int* in_sizes, int n_in,
                              void* d_out, int out_size, void* d_ws, size_t ws_size,
                              hipStream_t stream)
{
    const float* x      = (const float*)d_in[0];
    const float* conv_w = (const float*)d_in[1];
    const float* conv_g = (const float*)d_in[2];
    const float* conv_b = (const float*)d_in[3];
    const float* w1  = (const float*)d_in[4];
    const float* b1  = (const float*)d_in[5];
    const float* g1  = (const float*)d_in[6];
    const float* bt1 = (const float*)d_in[7];
    const float* w2  = (const float*)d_in[8];
    const float* b2  = (const float*)d_in[9];
    const float* g2  = (const float*)d_in[10];
    const float* bt2 = (const float*)d_in[11];
    const float* w3  = (const float*)d_in[12];
    const float* b3  = (const float*)d_in[13];
    const float* g3  = (const float*)d_in[14];
    const float* bt3 = (const float*)d_in[15];
    const float* w4  = (const float*)d_in[16];
    const float* b4  = (const float*)d_in[17];
    const float* w5  = (const float*)d_in[18];
    const float* b5  = (const float*)d_in[19];

    char* p = (char*)d_ws;
    auto take = [&](size_t bytes) -> char* {
        char* r = p; p += (bytes + 255) & ~(size_t)255; return r;
    };
    double* S    = (double*)take(27 * 8);
    double* sum1 = (double*)take(64 * 8);
    double* sq1  = (double*)take(64 * 8);
    double* sum2 = (double*)take(128 * 8);
    double* sq2  = (double*)take(128 * 8);
    double* sum3 = (double*)take(128 * 8);
    double* sq3  = (double*)take(128 * 8);
    size_t zero_bytes = (size_t)(p - (char*)d_ws);
    float* pmaxg  = (float*)take((size_t)512 * 128 * 4);     // 256 KB
    float* pming  = (float*)take((size_t)512 * 128 * 4);     // 256 KB
    float* mm     = (float*)take((size_t)NROWS * 128 * 4);   // 16 MB
    float* maxh   = mm;
    float* minh   = mm + (size_t)NROWS * 64;
    float* y1     = (float*)take((size_t)NROWS * 64 * 4);    // 8 MB
    float* y2     = (float*)take((size_t)NROWS * 128 * 4);   // 16 MB

    hipMemsetAsync(d_ws, 0, zero_bytes, stream);
    knn_feat_kernel<<<dim3(NB * 64), dim3(256), 0, stream>>>(x, conv_w, maxh, minh, S);

    mlp_gemm<64,64,true,false,true>    <<<dim3(512), dim3(256), 0, stream>>>(
        maxh, minh, S, nullptr, conv_g, conv_b, conv_w, w1, b1, y1, sum1, sq1, nullptr, nullptr);
    mlp_gemm<64,128,false,false,false> <<<dim3(512), dim3(256), 0, stream>>>(
        y1, y1, sum1, sq1, g1, bt1, nullptr, w2, b2, y2, sum2, sq2, nullptr, nullptr);
    mlp_gemm<128,128,false,true,false> <<<dim3(512), dim3(256), 0, stream>>>(
        y2, y2, sum2, sq2, g2, bt2, nullptr, w3, b3, nullptr, sum3, sq3, pmaxg, pming);

    headpool_kernel<<<dim3(NB), dim3(256), 0, stream>>>(
        pmaxg, pming, sum3, sq3, g3, bt3, w4, b4, w5, b5, (float*)d_out);
}

// Round 11
// 374.976 us; speedup vs baseline: 2.1303x; 1.1139x over previous
//
#include <hip/hip_runtime.h>
#include <math.h>

#define NB   16
#define NPTS 2048
#define KNBR 20
#define SCAP 128                 // survivor cap = 2 regs/lane (E~80, +5 sigma)
#define NROWS (NB*NPTS)          // 32768
#define CONV_M ((double)(NB)*(double)(NPTS)*(double)(KNBR))
#define ROW_M  ((double)NROWS)
#define BN_EPS 1e-5
#define LSLOPE 0.2f

__device__ __forceinline__ float lrelu(float v) { return v >= 0.f ? v : LSLOPE * v; }

// candidate staging: (2x, 2y, 2z, -|p|^2)   query: (x, y, z, -|q|^2)
__device__ __forceinline__ float4 stage4(float px, float py, float pz)
{
    return make_float4(px + px, py + py, pz + pz,
                       -fmaf(px, px, fmaf(py, py, pz * pz)));
}

// d = 2<q,c> - |q|^2 - |c|^2  (same op order as all prior rounds)
__device__ __forceinline__ float dist_eval(float4 q, float4 c)
{
    float t = fmaf(c.x, q.x, fmaf(c.y, q.y, fmaf(c.z, q.z, q.w)));
    return t + c.w;
}

// pair-insert of sorted (t0 >= t1) into sorted-desc bestv[20]
__device__ __forceinline__ void pair_insert_sorted(float (&bestv)[KNBR], float t0, float t1)
{
#pragma unroll
    for (int j = 0; j < KNBR; ++j) {
        float bj = bestv[j];
        float nb  = fmaxf(bj, t0);
        float nt0 = __builtin_amdgcn_fmed3f(bj, t0, t1);
        float nt1 = fminf(bj, t1);
        bestv[j] = nb;
        t0 = nt0; t1 = nt1;
    }
}

// order-preserving f32 <-> u32 map
__device__ __forceinline__ unsigned omap(float f)
{
    unsigned b = __float_as_uint(f);
    return b ^ (unsigned)(((int)b >> 31) | (int)0x80000000);
}
__device__ __forceinline__ float ounmap(unsigned u)
{
    unsigned b = (u & 0x80000000u) ? (u ^ 0x80000000u) : ~u;
    return __uint_as_float(b);
}

// ---------------------------------------------------------------------------
// Fused KNN (sample-bound -> filter -> 8-way-interleaved bisect) + index
// recovery + edge-conv. Block = (b, 32 queries), 256 threads.
// A: thread=(query,64-chunk of first 512): lane-local pair-cascade top-20 +
//    shfl tree-merge -> L = exact 20th of 512-sample (lower bound on d20).
// B: wave-per-query full scan; ballot-compact survivor VALUES (d >= L) to
//    LDS, then load into 2 regs/lane per query (8 queries -> 16 VGPRs).
// C: 32-step bisection, 8 independent query-chains INTERLEAVED per step
//    (pure VALU/SALU throughput, no dependent-chain stall) -> exact d20.
//    Overflow (cnt > 128) fallback re-evaluates (rare, still exact).
// Recovery: ballot/prefix rescan (d >= thresh), ascending, tie-exact.
// ---------------------------------------------------------------------------
__global__ __launch_bounds__(256) void knn_feat_kernel(const float* __restrict__ x,
        const float* __restrict__ conv_w,
        float* __restrict__ maxh, float* __restrict__ minh, double* __restrict__ S)
{
    __shared__ float4 pts[NPTS];                       // 32 KB
    __shared__ float  sval[32][SCAP];                  // 16 KB survivor values
    __shared__ float  tbuf[32];                        // L per query
    __shared__ unsigned short idxl[32][KNBR];
    __shared__ float  featw[4][KNBR][6];
    __shared__ double sred[4][27];
    const int b  = blockIdx.x >> 6;
    const int qg = blockIdx.x & 63;
    const int wv = threadIdx.x >> 6, lane = threadIdx.x & 63;
    const float* xb = x + (size_t)b * NPTS * 3;
    for (int i = threadIdx.x; i < NPTS; i += 256)
        pts[i] = stage4(xb[i*3+0], xb[i*3+1], xb[i*3+2]);
    __syncthreads();

    // ---- phase A: sample lower bound L (thread = query x 64-chunk) ----
    {
        const int qi = threadIdx.x >> 3;       // 0..31
        const int c  = threadIdx.x & 7;        // chunk 0..7 of first 512
        const int n  = qg * 32 + qi;
        const float4 qc = pts[n];
        const float4 q = make_float4(0.5f*qc.x, 0.5f*qc.y, 0.5f*qc.z, qc.w);
        float bestv[KNBR];
#pragma unroll
        for (int j = 0; j < KNBR; ++j) bestv[j] = -__builtin_inff();
        for (int m = 0; m < 64; m += 2) {
            const int j0 = c*64 + ((m + c) & 63);      // bank-spread rotation
            const int j1 = c*64 + ((m + 1 + c) & 63);
            float d0 = dist_eval(q, pts[j0]);
            float d1 = dist_eval(q, pts[j1]);
            pair_insert_sorted(bestv, fmaxf(d0, d1), fminf(d0, d1));
        }
        // tree-merge over the 8 chunk-threads (lanes differ in bits 0..2)
#pragma unroll
        for (int lev = 1; lev <= 4; lev <<= 1) {
            float orig[KNBR];
#pragma unroll
            for (int j = 0; j < KNBR; ++j) orig[j] = bestv[j];
            for (int i = 0; i < KNBR; i += 2) {
                float nb0 = __shfl_xor(orig[i],   lev);
                float nb1 = __shfl_xor(orig[i+1], lev);
                if (!__any(nb0 > bestv[KNBR-1])) break;
                pair_insert_sorted(bestv, nb0, nb1);
            }
        }
        if (c == 0) tbuf[qi] = bestv[KNBR-1];   // L = exact 20th of 512-sample
    }
    // no barrier needed: tbuf/sval/idxl flow is same-wave throughout

    // ---- phase B: filter + compact survivor values, wave per 8 queries ----
    const unsigned long long below = (1ull << lane) - 1ull;
    unsigned u0[8], u1[8];
    int cnts[8];
#pragma unroll
    for (int p8 = 0; p8 < 8; ++p8) {
        const int p = wv * 8 + p8;
        const int n = qg * 32 + p;
        const float4 qc = pts[n];
        const float4 q = make_float4(0.5f*qc.x, 0.5f*qc.y, 0.5f*qc.z, qc.w);
        const float L = tbuf[p];
        int cnt = 0;
        for (int it = 0; it < 32; ++it) {
            float d = dist_eval(q, pts[it*64 + lane]);
            const bool hit = (d >= L);
            unsigned long long mask = __ballot(hit);
            int pos = cnt + __popcll(mask & below);
            if (hit && pos < SCAP) sval[p][pos] = d;
            cnt += __popcll(mask);
        }
        cnts[p8] = cnt;
        u0[p8] = (lane      < cnt) ? omap(sval[p][lane])      : 0u;
        u1[p8] = (lane + 64 < cnt) ? omap(sval[p][lane + 64]) : 0u;
    }

    // ---- phase C: 8-way interleaved 32-step bisection (throughput-bound) ----
    unsigned lo[8], hi[8];
#pragma unroll
    for (int p8 = 0; p8 < 8; ++p8) { lo[p8] = 0u; hi[p8] = 0xFFFFFFFFu; }
    for (int s = 0; s < 32; ++s) {
#pragma unroll
        for (int p8 = 0; p8 < 8; ++p8) {
            const unsigned mid = lo[p8] + ((hi[p8] - lo[p8]) >> 1);
            const int c2 = __popcll(__ballot(u0[p8] >= mid))
                         + __popcll(__ballot(u1[p8] >= mid));
            const bool ge = (c2 >= KNBR);
            lo[p8] = ge ? mid : lo[p8];
            hi[p8] = ge ? hi[p8] : mid;
        }
    }

    // ---- recovery: thresh per query (fallback if overflow), rescan ----
#pragma unroll
    for (int p8 = 0; p8 < 8; ++p8) {
        const int p = wv * 8 + p8;
        const int n = qg * 32 + p;
        const float4 qc = pts[n];
        const float4 q = make_float4(0.5f*qc.x, 0.5f*qc.y, 0.5f*qc.z, qc.w);
        float thresh;
        if (cnts[p8] <= SCAP) {
            thresh = ounmap(lo[p8]);
        } else {
            // rare overflow: bisect with re-evaluated distances (still exact)
            unsigned flo = 0u, fhi = 0xFFFFFFFFu;
            for (int s = 0; s < 32; ++s) {
                unsigned mid = flo + ((fhi - flo) >> 1);
                int c2 = 0;
                for (int it = 0; it < 32; ++it) {
                    float d = dist_eval(q, pts[it*64 + lane]);
                    c2 += __popcll(__ballot(omap(d) >= mid));
                }
                bool ge = (c2 >= KNBR);
                flo = ge ? mid : flo;
                fhi = ge ? fhi : mid;
            }
            thresh = ounmap(flo);
        }
        int cnt2 = 0;
        for (int it = 0; it < 32; ++it) {
            float d = dist_eval(q, pts[it*64 + lane]);
            const bool hit = (d >= thresh);
            unsigned long long mask = __ballot(hit);
            int pos = cnt2 + __popcll(mask & below);
            if (hit && pos < KNBR)
                idxl[p][pos] = (unsigned short)(it*64 + lane);
            cnt2 += __popcll(mask);
        }
    }

    // ---- edge conv (unchanged) ----
    float cw[6];
#pragma unroll
    for (int c = 0; c < 6; ++c) cw[c] = conv_w[lane*6 + c];
    int pa_ = 0, pb_ = 0;
    if (lane >= 6 && lane < 27) {
        int t = lane - 6, a = 0;
        while (t >= 6 - a) { t -= 6 - a; ++a; }
        pa_ = a; pb_ = a + t;
    }
    double acc = 0.0;
    for (int i = 0; i < 8; ++i) {
        const int p = wv * 8 + i;
        const int nn = qg * 32 + p;
        const size_t bp = (size_t)b * NPTS + nn;
        const float4 Ci = pts[nn];
        const float xi0 = 0.5f*Ci.x, xi1 = 0.5f*Ci.y, xi2 = 0.5f*Ci.z;
        float f0=0,f1=0,f2=0,f3=0,f4=0,f5=0;
        if (lane < KNBR) {
            const float4 Cj = pts[idxl[p][lane]];
            f0 = 0.5f*(Cj.x - Ci.x);   // == fl(xj - xi) exactly
            f1 = 0.5f*(Cj.y - Ci.y);
            f2 = 0.5f*(Cj.z - Ci.z);
            f3 = xi0; f4 = xi1; f5 = xi2;
        }
        __syncthreads();
        if (lane < KNBR) {
            featw[wv][lane][0]=f0; featw[wv][lane][1]=f1; featw[wv][lane][2]=f2;
            featw[wv][lane][3]=f3; featw[wv][lane][4]=f4; featw[wv][lane][5]=f5;
        }
        __syncthreads();
        float vmax = -__builtin_inff(), vmin = __builtin_inff();
#pragma unroll
        for (int k = 0; k < KNBR; ++k) {
            float h = featw[wv][k][0] * cw[0];
            h = fmaf(featw[wv][k][1], cw[1], h);
            h = fmaf(featw[wv][k][2], cw[2], h);
            h = fmaf(featw[wv][k][3], cw[3], h);
            h = fmaf(featw[wv][k][4], cw[4], h);
            h = fmaf(featw[wv][k][5], cw[5], h);
            vmax = fmaxf(vmax, h); vmin = fminf(vmin, h);
        }
        maxh[bp*64 + lane] = vmax;
        minh[bp*64 + lane] = vmin;
        if (lane < 6) {
            double s = 0;
#pragma unroll
            for (int k = 0; k < KNBR; ++k) s += (double)featw[wv][k][lane];
            acc += s;
        } else if (lane < 27) {
            double s = 0;
#pragma unroll
            for (int k = 0; k < KNBR; ++k)
                s += (double)featw[wv][k][pa_] * (double)featw[wv][k][pb_];
            acc += s;
        }
    }
    if (lane < 27) sred[wv][lane] = acc;
    __syncthreads();
    if (threadIdx.x < 27) {
        double tot = sred[0][threadIdx.x] + sred[1][threadIdx.x]
                   + sred[2][threadIdx.x] + sred[3][threadIdx.x];
        atomicAdd(&S[threadIdx.x], tot);
    }
}

// ---------------------------------------------------------------------------
// MLP GEMM with in-kernel BN scale/shift derivation (identical double math
// per block -> identical floats).
// ---------------------------------------------------------------------------
template<int K, int N, bool SEL, bool POOLOUT, bool STATS0>
__global__ __launch_bounds__(256) void mlp_gemm(const float* __restrict__ A,
        const float* __restrict__ A2,
        const double* __restrict__ st_a, const double* __restrict__ st_b,
        const float* __restrict__ st_g, const float* __restrict__ st_bt,
        const float* __restrict__ cwm,
        const float* __restrict__ W, const float* __restrict__ bias,
        float* __restrict__ Y, double* __restrict__ sum, double* __restrict__ sq,
        float* __restrict__ pmax_g, float* __restrict__ pmin_g)
{
    constexpr int CPT = N / 16;                 // cols per thread (4 or 8)
    __shared__ float As[64 * 64];               // [k][row^swz], 16 KB
    __shared__ float Ws[64 * N];                // [k][n]
    __shared__ __align__(16) float s_scale[K], s_shift[K];
    const int tid = threadIdx.x;
    if (tid < K) {
        const int o = tid;
        if (STATS0) {
            double w[6];
#pragma unroll
            for (int c = 0; c < 6; ++c) w[c] = (double)cwm[o*6 + c];
            double mean = 0.0;
#pragma unroll
            for (int c = 0; c < 6; ++c) mean += w[c] * st_a[c];
            mean /= CONV_M;
            double ey2 = 0.0;
            int t = 6;
#pragma unroll
            for (int a = 0; a < 6; ++a)
#pragma unroll
                for (int b2 = a; b2 < 6; ++b2) {
                    double coef = (a == b2) ? 1.0 : 2.0;
                    ey2 += coef * w[a] * w[b2] * st_a[t];
                    ++t;
                }
            ey2 /= CONV_M;
            double var = ey2 - mean * mean;
            double sc = (double)st_g[o] / sqrt(var + BN_EPS);
            s_scale[o] = (float)sc;
            s_shift[o] = (float)((double)st_bt[o] - mean * sc);
        } else {
            double m = st_a[o] / ROW_M;
            double v = st_b[o] / ROW_M - m * m;
            double sc = (double)st_g[o] / sqrt(v + BN_EPS);
            s_scale[o] = (float)sc;
            s_shift[o] = (float)((double)st_bt[o] - m * sc);
        }
    }
    const int row0 = blockIdx.x * 64;
    const int ct = tid & 15, rt = tid >> 4;
    float acc[4][CPT];
#pragma unroll
    for (int rr = 0; rr < 4; ++rr)
#pragma unroll
        for (int cc = 0; cc < CPT; ++cc) acc[rr][cc] = bias[ct*CPT + cc];
    __syncthreads();

    for (int kk = 0; kk < K/64; ++kk) {
        if (kk) __syncthreads();
#pragma unroll
        for (int i = 0; i < 4; ++i) {
            const int f   = i * 256 + tid;
            const int k4  = f & 15;
            const int row = f >> 4;
            const int kg  = kk*64 + k4*4;
            float4 m = *(const float4*)(A + (size_t)(row0+row)*K + kg);
            const float4 s4 = *(const float4*)(&s_scale[kg]);
            const float4 h4 = *(const float4*)(&s_shift[kg]);
            if (SEL) {
                float4 m2 = *(const float4*)(A2 + (size_t)(row0+row)*K + kg);
                m.x = s4.x >= 0.f ? m.x : m2.x;
                m.y = s4.y >= 0.f ? m.y : m2.y;
                m.z = s4.z >= 0.f ? m.z : m2.z;
                m.w = s4.w >= 0.f ? m.w : m2.w;
            }
            const int rsw = row ^ ((k4 & 7) << 2);
            As[(k4*4+0)*64 + rsw] = lrelu(fmaf(s4.x, m.x, h4.x));
            As[(k4*4+1)*64 + rsw] = lrelu(fmaf(s4.y, m.y, h4.y));
            As[(k4*4+2)*64 + rsw] = lrelu(fmaf(s4.z, m.z, h4.z));
            As[(k4*4+3)*64 + rsw] = lrelu(fmaf(s4.w, m.w, h4.w));
        }
#pragma unroll
        for (int i = 0; i < N/16; ++i) {
            const int f    = i * 256 + tid;
            const int col4 = f & (N/4 - 1);
            const int krow = f / (N/4);
            *(float4*)(&Ws[krow*N + col4*4]) =
                *(const float4*)(W + (size_t)(kk*64 + krow)*N + col4*4);
        }
        __syncthreads();
#pragma unroll 4
        for (int k = 0; k < 64; ++k) {
            const int sw = ((k >> 2) & 7) << 2;
            const float4 a0 = *(const float4*)(&As[k*64 + ((rt*4) ^ sw)]);
            float a_[4] = {a0.x, a0.y, a0.z, a0.w};
            float w_[CPT];
#pragma unroll
            for (int v = 0; v < CPT/4; ++v) {
                const float4 wv4 = *(const float4*)(&Ws[k*N + ct*CPT + v*4]);
                w_[v*4+0] = wv4.x; w_[v*4+1] = wv4.y; w_[v*4+2] = wv4.z; w_[v*4+3] = wv4.w;
            }
#pragma unroll
            for (int rr = 0; rr < 4; ++rr)
#pragma unroll
                for (int cc = 0; cc < CPT; ++cc)
                    acc[rr][cc] = fmaf(a_[rr], w_[cc], acc[rr][cc]);
        }
    }
    if (!POOLOUT) {
#pragma unroll
        for (int rr = 0; rr < 4; ++rr) {
            float* yo = Y + (size_t)(row0 + rt*4 + rr)*N + ct*CPT;
#pragma unroll
            for (int v = 0; v < CPT/4; ++v)
                *(float4*)(yo + v*4) = make_float4(acc[rr][v*4+0], acc[rr][v*4+1],
                                                   acc[rr][v*4+2], acc[rr][v*4+3]);
        }
    }
    __syncthreads();                  // LDS dead; reuse As/Ws
    float* cr  = As;                  // [2N] column sum/sq partials
    float* pmx = As + 512;            // [16][N] per-rt max
    float* pmn = Ws;                  // [16][N] per-rt min
    if (tid < 2*N) cr[tid] = 0.f;
    if (POOLOUT) {
#pragma unroll
        for (int cc = 0; cc < CPT; ++cc) {
            float vmax = fmaxf(fmaxf(acc[0][cc], acc[1][cc]), fmaxf(acc[2][cc], acc[3][cc]));
            float vmin = fminf(fminf(acc[0][cc], acc[1][cc]), fminf(acc[2][cc], acc[3][cc]));
            pmx[rt*N + ct*CPT + cc] = vmax;
            pmn[rt*N + ct*CPT + cc] = vmin;
        }
    }
    __syncthreads();
#pragma unroll
    for (int cc = 0; cc < CPT; ++cc) {
        float s = acc[0][cc] + acc[1][cc] + acc[2][cc] + acc[3][cc];
        float q = fmaf(acc[0][cc], acc[0][cc], 0.f);
        q = fmaf(acc[1][cc], acc[1][cc], q);
        q = fmaf(acc[2][cc], acc[2][cc], q);
        q = fmaf(acc[3][cc], acc[3][cc], q);
        atomicAdd(&cr[ct*CPT + cc], s);
        atomicAdd(&cr[N + ct*CPT + cc], q);
    }
    float rm = 0.f, rn = 0.f;
    if (POOLOUT && tid < N) {
        rm = pmx[tid]; rn = pmn[tid];
#pragma unroll
        for (int r = 1; r < 16; ++r) {
            rm = fmaxf(rm, pmx[r*N + tid]);
            rn = fminf(rn, pmn[r*N + tid]);
        }
    }
    __syncthreads();
    if (tid < N) {
        atomicAdd(&sum[tid], (double)cr[tid]);
        atomicAdd(&sq[tid],  (double)cr[N + tid]);
        if (POOLOUT) {
            pmax_g[(size_t)blockIdx.x * N + tid] = rm;
            pmin_g[(size_t)blockIdx.x * N + tid] = rn;
        }
    }
}

// ---------------------------------------------------------------------------
// Fused BN3-derive + pool-finish + head. Block = batch b.
// ---------------------------------------------------------------------------
__global__ __launch_bounds__(256) void headpool_kernel(const float* __restrict__ pmax_g,
        const float* __restrict__ pmin_g,
        const double* __restrict__ sum3, const double* __restrict__ sq3,
        const float* __restrict__ g3, const float* __restrict__ bt3,
        const float* __restrict__ w4, const float* __restrict__ b4,
        const float* __restrict__ w5, const float* __restrict__ b5,
        float* __restrict__ out)
{
    __shared__ float xr[128];
    __shared__ float hh[512];
    const int b = blockIdx.x, t = threadIdx.x;
    if (t < 128) {
        double m_ = sum3[t] / ROW_M;
        double v_ = sq3[t] / ROW_M - m_ * m_;
        double scd = (double)g3[t] / sqrt(v_ + BN_EPS);
        const float sc = (float)scd;
        const float sh = (float)((double)bt3[t] - m_ * scd);
        const float* pm = pmax_g + (size_t)b * 32 * 128 + t;
        const float* pn = pmin_g + (size_t)b * 32 * 128 + t;
        float m = pm[0], n_ = pn[0];
#pragma unroll
        for (int r = 1; r < 32; ++r) {
            m  = fmaxf(m,  pm[r*128]);
            n_ = fminf(n_, pn[r*128]);
        }
        xr[t] = lrelu(sc >= 0.f ? fmaf(sc, m, sh) : fmaf(sc, n_, sh));
    }
    __syncthreads();
    float h0 = b4[t], h1 = b4[t + 256];
    for (int c = 0; c < 128; ++c) {
        float xc = xr[c];
        h0 = fmaf(xc, w4[c*512 + t],       h0);
        h1 = fmaf(xc, w4[c*512 + t + 256], h1);
    }
    hh[t]       = lrelu(h0);
    hh[t + 256] = lrelu(h1);
    __syncthreads();
    float acc = b5[t];
    for (int c = 0; c < 512; ++c)
        acc = fmaf(hh[c], w5[c*256 + t], acc);
    out[b*256 + t] = acc;
}

extern "C" void kernel_launch(void* const* d_in, const int* in_sizes, int n_in,
                              void* d_out, int out_size, void* d_ws, size_t ws_size,
                              hipStream_t stream)
{
    const float* x      = (const float*)d_in[0];
    const float* conv_w = (const float*)d_in[1];
    const float* conv_g = (const float*)d_in[2];
    const float* conv_b = (const float*)d_in[3];
    const float* w1  = (const float*)d_in[4];
    const float* b1  = (const float*)d_in[5];
    const float* g1  = (const float*)d_in[6];
    const float* bt1 = (const float*)d_in[7];
    const float* w2  = (const float*)d_in[8];
    const float* b2  = (const float*)d_in[9];
    const float* g2  = (const float*)d_in[10];
    const float* bt2 = (const float*)d_in[11];
    const float* w3  = (const float*)d_in[12];
    const float* b3  = (const float*)d_in[13];
    const float* g3  = (const float*)d_in[14];
    const float* bt3 = (const float*)d_in[15];
    const float* w4  = (const float*)d_in[16];
    const float* b4  = (const float*)d_in[17];
    const float* w5  = (const float*)d_in[18];
    const float* b5  = (const float*)d_in[19];

    char* p = (char*)d_ws;
    auto take = [&](size_t bytes) -> char* {
        char* r = p; p += (bytes + 255) & ~(size_t)255; return r;
    };
    double* S    = (double*)take(27 * 8);
    double* sum1 = (double*)take(64 * 8);
    double* sq1  = (double*)take(64 * 8);
    double* sum2 = (double*)take(128 * 8);
    double* sq2  = (double*)take(128 * 8);
    double* sum3 = (double*)take(128 * 8);
    double* sq3  = (double*)take(128 * 8);
    size_t zero_bytes = (size_t)(p - (char*)d_ws);
    float* pmaxg  = (float*)take((size_t)512 * 128 * 4);     // 256 KB
    float* pming  = (float*)take((size_t)512 * 128 * 4);     // 256 KB
    float* mm     = (float*)take((size_t)NROWS * 128 * 4);   // 16 MB
    float* maxh   = mm;
    float* minh   = mm + (size_t)NROWS * 64;
    float* y1     = (float*)take((size_t)NROWS * 64 * 4);    // 8 MB
    float* y2     = (float*)take((size_t)NROWS * 128 * 4);   // 16 MB

    hipMemsetAsync(d_ws, 0, zero_bytes, stream);
    knn_feat_kernel<<<dim3(NB * 64), dim3(256), 0, stream>>>(x, conv_w, maxh, minh, S);

    mlp_gemm<64,64,true,false,true>    <<<dim3(512), dim3(256), 0, stream>>>(
        maxh, minh, S, nullptr, conv_g, conv_b, conv_w, w1, b1, y1, sum1, sq1, nullptr, nullptr);
    mlp_gemm<64,128,false,false,false> <<<dim3(512), dim3(256), 0, stream>>>(
        y1, y1, sum1, sq1, g1, bt1, nullptr, w2, b2, y2, sum2, sq2, nullptr, nullptr);
    mlp_gemm<128,128,false,true,false> <<<dim3(512), dim3(256), 0, stream>>>(
        y2, y2, sum2, sq2, g2, bt2, nullptr, w3, b3, nullptr, sum3, sq3, pmaxg, pming);

    headpool_kernel<<<dim3(NB), dim3(256), 0, stream>>>(
        pmaxg, pming, sum3, sq3, g3, bt3, w4, b4, w5, b5, (float*)d_out);
}